// Round 1
// 481.409 us; speedup vs baseline: 1.1188x; 1.1188x over previous
//
#include <hip/hip_runtime.h>
#include <hip/hip_bf16.h>

// LCA sparsifier: 10 iterations of v = 0.9v + 0.1u - 0.1*(a@G); a = soft(v, lam)
// Fused persistent-row design: each block owns 64 rows across all 10 iterations.
// R1 changes vs baseline:
//  - 1024-thread blocks, 16 waves, wave tile 64x32 (acc[2] + uu[2] = 64 regs +
//    ~50 VGPR <= 128 unified) -> 16 waves/CU (4/SIMD) instead of 8 (2/SIMD).
//  - per-block kk stagger (s = (bid>>3)&31) decorrelates the all-blocks-lockstep
//    sweep of G through L2 (same-line contention).
//  - double-buffered sA -> ONE __syncthreads per iteration; epilogue of fast
//    waves overlaps MFMA of slow waves.

typedef __attribute__((ext_vector_type(8))) short bf16x8;
typedef __attribute__((ext_vector_type(16))) float f32x16;

#define ETA 0.1f

__device__ __forceinline__ unsigned short f2bf(float f) {
  union { float f; unsigned u; } x; x.f = f;
  unsigned r = x.u + 0x7fffu + ((x.u >> 16) & 1u);  // round-to-nearest-even
  return (unsigned short)(r >> 16);
}

// ---- prep: G = 0.5(Graw + Graw^T), zero diag, bf16, swizzled into
// mfma_f32_32x32x16_bf16 B-fragment order: B[k][n], lane = (n&31) + 32*((k>>3)&1),
// j = k&7, frag index = (kk*16 + ct)*64 + lane  with kk=k>>4, ct=n>>5.
__global__ void prep_G(const float* __restrict__ Graw, unsigned short* __restrict__ Gb) {
  int idx = blockIdx.x * blockDim.x + threadIdx.x;  // 512*512 elements
  int k = idx >> 9, n = idx & 511;
  float g = 0.5f * (Graw[k * 512 + n] + Graw[n * 512 + k]);
  if (k == n) g = 0.f;
  int kk = k >> 4, ct = n >> 5;
  int lane = (n & 31) + (((k >> 3) & 1) << 5);
  int j = k & 7;
  Gb[((((kk * 16 + ct) * 64) + lane) << 3) + j] = f2bf(g);
}

__global__ __launch_bounds__(1024) void lca_kernel(
    const float* __restrict__ u_g, const unsigned short* __restrict__ Gb,
    const float* __restrict__ log_lam, float* __restrict__ out) {
  // a-buffer: double-buffered 64 rows x 512 cols bf16, row stride 520
  // (1040B = 16*65 -> the 8-lane b128 phases of an A-fragment read cover all
  // 8 bank groups; measured 0 bank conflicts).
  __shared__ unsigned short sA[2][64 * 520];

  const int tid = threadIdx.x;
  const int lane = tid & 63;
  const int wave = tid >> 6;           // 0..15, owns cols [wave*32, wave*32+32)
  const int R0 = blockIdx.x * 64;      // block's global row base
  const int cl = lane & 31;            // col within 32-tile / A-row within tile
  const int rquad = (lane >> 5) * 4;   // C-layout row contribution of lane-half
  const int C0 = wave * 32;
  const int s = (blockIdx.x >> 3) & 31;  // kk stagger: same-XCD blocks offset

  const float lam = expf(log_lam[0]);

  f32x16 acc[2];  // [row-tile], C layout: col=lane&31,
                  // row=(reg&3)+8*(reg>>2)+4*(lane>>5)
  f32x16 uu[2];

  // ---- load u in C layout; init acc = -u  (t=0: v=0, P=0 -> C = -9v-u = -u)
  #pragma unroll
  for (int rt = 0; rt < 2; ++rt) {
    const float* base = u_g + (R0 + rt * 32 + rquad) * 512 + C0 + cl;
    f32x16 t;
    #pragma unroll
    for (int reg = 0; reg < 16; ++reg) {
      const int rofs = (reg & 3) + 8 * (reg >> 2);
      t[reg] = base[rofs * 512];
    }
    uu[rt] = t;
    acc[rt] = -t;
  }

  // epilogue: a = soft(-ETA*acc) -> LDS buffer (bf16, A layout, padded 520);
  // then re-init acc for next iteration: acc = 0.9*acc - u
  auto epilogue = [&](unsigned short* sbuf) {
    #pragma unroll
    for (int rt = 0; rt < 2; ++rt) {
      unsigned short* sa = &sbuf[(rt * 32 + rquad) * 520 + C0 + cl];
      #pragma unroll
      for (int reg = 0; reg < 16; ++reg) {
        const int rofs = (reg & 3) + 8 * (reg >> 2);
        float v = -ETA * acc[rt][reg];
        float av = copysignf(fmaxf(fabsf(v) - lam, 0.f), v);
        sa[rofs * 520] = f2bf(av);
      }
      acc[rt] = 0.9f * acc[rt] - uu[rt];
    }
  };

  // t = 0: P = 0, GEMM skipped (a_0 = 0). Writes a_1 into buffer 0.
  epilogue(sA[0]);
  __syncthreads();

  const bf16x8* gb = (const bf16x8*)Gb;
  const int bbase = wave * 64 + lane;  // B-frag index for col-tile ct = wave

  #pragma unroll 1
  for (int t = 1; t < 10; ++t) {
    // GEMM t reads a_t from buffer (t-1)&1 == (t+1)&1
    // A-fragment: A[m][k], m = lane&31 (local row), k = kko*16 + (lane>>5)*8 + j
    const unsigned short* paRow = sA[(t + 1) & 1] + cl * 520 + ((lane >> 5) << 3);
    #pragma unroll 4
    for (int kk = 0; kk < 32; ++kk) {
      const int kko = (kk + s) & 31;
      bf16x8 a0 = *(const bf16x8*)(paRow + kko * 16);
      bf16x8 a1 = *(const bf16x8*)(paRow + 32 * 520 + kko * 16);
      bf16x8 b0 = gb[bbase + kko * 1024];
      acc[0] = __builtin_amdgcn_mfma_f32_32x32x16_bf16(a0, b0, acc[0], 0, 0, 0);
      acc[1] = __builtin_amdgcn_mfma_f32_32x32x16_bf16(a1, b0, acc[1], 0, 0, 0);
    }
    // epilogue writes the OTHER buffer -> no barrier needed between GEMM read
    // and epilogue write; single barrier publishes a_{t+1} for the next GEMM.
    if (t < 9) {
      epilogue(sA[t & 1]);
      __syncthreads();
    }
  }

  // ---- final output: a_10 = soft(-ETA * acc)
  #pragma unroll
  for (int rt = 0; rt < 2; ++rt) {
    float* ob = out + (R0 + rt * 32 + rquad) * 512 + C0 + cl;
    #pragma unroll
    for (int reg = 0; reg < 16; ++reg) {
      const int rofs = (reg & 3) + 8 * (reg >> 2);
      float v = -ETA * acc[rt][reg];
      ob[rofs * 512] = copysignf(fmaxf(fabsf(v) - lam, 0.f), v);
    }
  }
}

extern "C" void kernel_launch(void* const* d_in, const int* in_sizes, int n_in,
                              void* d_out, int out_size, void* d_ws, size_t ws_size,
                              hipStream_t stream) {
  const float* u = (const float*)d_in[0];
  const float* Graw = (const float*)d_in[1];
  const float* log_lam = (const float*)d_in[2];
  float* out = (float*)d_out;
  unsigned short* Gb = (unsigned short*)d_ws;  // 512*512*2 = 512 KB scratch

  prep_G<<<dim3(1024), dim3(256), 0, stream>>>(Graw, Gb);
  lca_kernel<<<dim3(1024), dim3(1024), 0, stream>>>(u, Gb, log_lam, out);
}